// Round 6
// baseline (268.688 us; speedup 1.0000x reference)
//
#include <hip/hip_runtime.h>
#include <hip/hip_bf16.h>
#include <math.h>

typedef __attribute__((ext_vector_type(8))) short short8;
typedef __attribute__((ext_vector_type(4))) float floatx4;

__device__ __forceinline__ unsigned short f2b(float f) {
  unsigned int u = __builtin_bit_cast(unsigned int, f);
  u += 0x7fffu + ((u >> 16) & 1u);
  return (unsigned short)(u >> 16);
}
__device__ __forceinline__ float b2f(unsigned short s) {
  unsigned int u = ((unsigned int)s) << 16;
  return __builtin_bit_cast(float, u);
}
__device__ __forceinline__ float sigm(float v) { return 1.f / (1.f + __expf(-v)); }
__device__ __forceinline__ float tanh_fast(float y) {
  float t = __expf(2.f * y);
  return 1.f - 2.f / (t + 1.f);
}

// ---------------------------------------------------------------------------
// Edge preprocessing
// ---------------------------------------------------------------------------
__global__ __launch_bounds__(1024) void detect_kernel(const unsigned int* __restrict__ ei,
                                                      long long n_u32, int* __restrict__ flag) {
  __shared__ int any;
  if (threadIdx.x == 0) any = 0;
  __syncthreads();
  int nz = 0;
  for (int rep = 0; rep < 4; ++rep) {
    long long idx = 2LL * (threadIdx.x + rep * 1024) + 1;
    if (idx < n_u32 && ei[idx] != 0u) nz = 1;
  }
  if (nz) atomicOr(&any, 1);
  __syncthreads();
  if (threadIdx.x == 0) *flag = any;  // 1 -> int32 data, 0 -> int64 data
}

__device__ __forceinline__ void load_edge(const void* ei, int E, int flag, int i,
                                          int& s, int& d) {
  if (flag == 0) {
    const long long* p = (const long long*)ei;
    s = (int)p[i];
    d = (int)p[(long long)E + i];
  } else {
    const int* p = (const int*)ei;
    s = p[i];
    d = p[E + i];
  }
}

__global__ __launch_bounds__(256) void hist_kernel(const void* __restrict__ ei, int E,
                                                   const int* __restrict__ flag,
                                                   int* __restrict__ deg) {
  int i = blockIdx.x * 256 + threadIdx.x;
  if (i >= E) return;
  int s, d;
  load_edge(ei, E, *flag, i, s, d);
  atomicAdd(&deg[d], 1);
}

// parallel scan, 3 kernels: per-1024-block sums -> 1-wave scan -> finalize
__global__ __launch_bounds__(256) void scan_partial(const int* __restrict__ deg,
                                                    int* __restrict__ bsum, int n) {
  __shared__ int ws[4];
  int base = blockIdx.x * 1024 + threadIdx.x * 4;
  int lane = threadIdx.x & 63, wid = threadIdx.x >> 6;
  int tot = 0;
  #pragma unroll
  for (int k = 0; k < 4; ++k) {
    int i = base + k;
    if (i < n) tot += deg[i];
  }
  #pragma unroll
  for (int ofs = 1; ofs < 64; ofs <<= 1) tot += __shfl_xor(tot, ofs, 64);
  if (lane == 0) ws[wid] = tot;
  __syncthreads();
  if (threadIdx.x == 0) bsum[blockIdx.x] = ws[0] + ws[1] + ws[2] + ws[3];
}

__global__ __launch_bounds__(64) void scan_bsums(int* __restrict__ bsum, int nb) {
  int lane = threadIdx.x;
  int carry = 0;
  for (int base = 0; base < nb; base += 64) {
    int i = base + lane;
    int v = (i < nb) ? bsum[i] : 0;
    int s = v;
    #pragma unroll
    for (int ofs = 1; ofs < 64; ofs <<= 1) {
      int t = __shfl_up(s, ofs, 64);
      if (lane >= ofs) s += t;
    }
    if (i < nb) bsum[i] = s - v + carry;           // exclusive
    int tot = __shfl(s, 63, 64);
    carry += tot;
  }
}

__global__ __launch_bounds__(256) void scan_final(const int* __restrict__ deg,
                                                  const int* __restrict__ bsum,
                                                  int* __restrict__ off,
                                                  int* __restrict__ cursor, int n) {
  __shared__ int ws[4];
  int lane = threadIdx.x & 63, wid = threadIdx.x >> 6;
  int base = blockIdx.x * 1024 + threadIdx.x * 4;
  int v[4];
  int tot = 0;
  #pragma unroll
  for (int k = 0; k < 4; ++k) {
    int i = base + k;
    v[k] = (i < n) ? deg[i] : 0;
    tot += v[k];
  }
  int s = tot;
  #pragma unroll
  for (int ofs = 1; ofs < 64; ofs <<= 1) {
    int t = __shfl_up(s, ofs, 64);
    if (lane >= ofs) s += t;
  }
  if (lane == 63) ws[wid] = s;
  __syncthreads();
  int wpre = 0;
  for (int ww = 0; ww < wid; ++ww) wpre += ws[ww];
  int p = bsum[blockIdx.x] + wpre + (s - tot);     // exclusive prefix of this thread
  if (blockIdx.x == 0 && threadIdx.x == 0) { off[0] = 0; cursor[0] = 0; }
  #pragma unroll
  for (int k = 0; k < 4; ++k) {
    int i = base + k;
    p += v[k];
    if (i < n) { off[i + 1] = p; cursor[i + 1] = p; }
  }
}

__global__ __launch_bounds__(256) void scatter_kernel(const void* __restrict__ ei, int E,
                                                      const int* __restrict__ flag,
                                                      int* __restrict__ cursor,
                                                      int* __restrict__ csr) {
  int i = blockIdx.x * 256 + threadIdx.x;
  if (i >= E) return;
  int s, d;
  load_edge(ei, E, *flag, i, s, d);
  int pos = atomicAdd(&cursor[d], 1);
  csr[pos] = s;
}

// weights -> transposed bf16 (B^T [N][K])
__global__ __launch_bounds__(256) void wprep(const float* __restrict__ Wl,
                                             const float* __restrict__ Wr,
                                             const float* __restrict__ W1,
                                             const float* __restrict__ W2,
                                             unsigned short* __restrict__ Btxw,
                                             unsigned short* __restrict__ Bt1,
                                             unsigned short* __restrict__ Bt2) {
  int idx = blockIdx.x * 256 + threadIdx.x;
  if (idx < 32768) {                         // Btxw[256][128]
    int nn = idx >> 7, k = idx & 127;
    float v = (nn < 128) ? Wl[k * 128 + nn] : Wr[k * 128 + (nn - 128)];
    Btxw[nn * 128 + k] = f2b(v);
  } else if (idx < 98304) {                  // Bt1[256][256] = W1^T
    int loc = idx - 32768;
    int nn = loc >> 8, k = loc & 255;
    Bt1[nn * 256 + k] = f2b(W1[k * 256 + nn]);
  } else {                                   // Bt2[128][256] = W2^T
    int loc = idx - 98304;
    int nn = loc >> 8, k = loc & 255;
    Bt2[nn * 256 + k] = f2b(W2[k * 128 + nn]);
  }
}

// ---------------------------------------------------------------------------
// xl|xr = x @ [Wl|Wr].  Block 64 rows, 4 waves; wave = 64 rows x 64 cols.
// B staged in 2 K-chunks (32 KB) with register prefetch; LDS 48 KB -> 3 blk/CU.
// Staging rule (rule #21): source LINEAR, LDS dest swizzled; reads same XOR.
// ---------------------------------------------------------------------------
__global__ __launch_bounds__(256) void gemm_xw(const float* __restrict__ x,
                                               const unsigned short* __restrict__ Bt,
                                               unsigned short* __restrict__ xl,
                                               unsigned short* __restrict__ xr, int n) {
  __shared__ char As[64 * 256];    // 64 rows x 128 bf16 (full K), 16 KB
  __shared__ char Bs[256 * 128];   // 256 N-rows x 64 K bf16 chunk, 32 KB
  int t = threadIdx.x;
  int w = t >> 6, l = t & 63;
  int row0 = blockIdx.x * 64;
  int l15 = l & 15, lhi = l >> 4;

  // stage A from f32: src linear, dest swizzled
  #pragma unroll
  for (int u_ = 0; u_ < 4; ++u_) {
    int unit = t + u_ * 256;
    int r = unit >> 4, slot = unit & 15;
    int grow = row0 + r;
    uint4 o = make_uint4(0, 0, 0, 0);
    if (grow < n) {
      const float* s = x + (size_t)grow * 128 + slot * 8;
      float4 f0 = *(const float4*)s, f1 = *(const float4*)(s + 4);
      o.x = (unsigned)f2b(f0.x) | ((unsigned)f2b(f0.y) << 16);
      o.y = (unsigned)f2b(f0.z) | ((unsigned)f2b(f0.w) << 16);
      o.z = (unsigned)f2b(f1.x) | ((unsigned)f2b(f1.y) << 16);
      o.w = (unsigned)f2b(f1.z) | ((unsigned)f2b(f1.w) << 16);
    }
    *(uint4*)(As + r * 256 + ((slot * 16) ^ ((r & 7) << 4))) = o;
  }

  floatx4 acc[4][4];
  #pragma unroll
  for (int mt = 0; mt < 4; ++mt)
    #pragma unroll
    for (int nt = 0; nt < 4; ++nt) acc[mt][nt] = (floatx4){0.f, 0.f, 0.f, 0.f};

  // prefetch B chunk ks=0 into registers
  uint4 breg[8];
  #pragma unroll
  for (int u_ = 0; u_ < 8; ++u_) {
    int unit = t + u_ * 256;
    int r = unit >> 3, b16 = unit & 7;
    breg[u_] = *(const uint4*)(Bt + (size_t)r * 128 + b16 * 8);
  }

  for (int ks = 0; ks < 2; ++ks) {
    #pragma unroll
    for (int u_ = 0; u_ < 8; ++u_) {
      int unit = t + u_ * 256;
      int r = unit >> 3, b16 = unit & 7;
      *(uint4*)(Bs + r * 128 + ((b16 * 16) ^ ((r & 7) << 4))) = breg[u_];
    }
    __syncthreads();
    if (ks == 0) {                 // issue next chunk during compute
      #pragma unroll
      for (int u_ = 0; u_ < 8; ++u_) {
        int unit = t + u_ * 256;
        int r = unit >> 3, b16 = unit & 7;
        breg[u_] = *(const uint4*)(Bt + (size_t)r * 128 + 64 + b16 * 8);
      }
    }
    #pragma unroll
    for (int kk = 0; kk < 2; ++kk) {
      int ka = ks * 128 + kk * 64 + lhi * 16;
      int kb = kk * 64 + lhi * 16;
      short8 a[4];
      #pragma unroll
      for (int mt = 0; mt < 4; ++mt) {
        int r = mt * 16 + l15;
        a[mt] = *(const short8*)(As + r * 256 + (ka ^ ((r & 7) << 4)));
      }
      #pragma unroll
      for (int nt = 0; nt < 4; ++nt) {
        int r = w * 64 + nt * 16 + l15;
        short8 b = *(const short8*)(Bs + r * 128 + (kb ^ ((r & 7) << 4)));
        #pragma unroll
        for (int mt = 0; mt < 4; ++mt)
          acc[mt][nt] = __builtin_amdgcn_mfma_f32_16x16x32_bf16(a[mt], b, acc[mt][nt], 0, 0, 0);
      }
    }
    __syncthreads();
  }

  #pragma unroll
  for (int mt = 0; mt < 4; ++mt)
    #pragma unroll
    for (int nt = 0; nt < 4; ++nt) {
      int col = w * 64 + nt * 16 + l15;
      int rbase = row0 + mt * 16 + lhi * 4;
      #pragma unroll
      for (int j = 0; j < 4; ++j) {
        int row = rbase + j;
        if (row >= n) continue;
        unsigned short v = f2b(acc[mt][nt][j]);
        if (col < 128) xl[(size_t)row * 128 + col] = v;
        else           xr[(size_t)row * 128 + (col - 128)] = v;
      }
    }
}

// ---------------------------------------------------------------------------
// One wave per node; lane l owns dims (2l, 2l+1); head = l>>4.
// ---------------------------------------------------------------------------
__global__ __launch_bounds__(256) void node_kernel(const unsigned int* __restrict__ xl32,
                                                   const unsigned int* __restrict__ xr32,
                                                   const float* __restrict__ att,
                                                   const float* __restrict__ bias,
                                                   const int* __restrict__ off,
                                                   const int* __restrict__ csr,
                                                   unsigned int* __restrict__ fout, int n) {
  int wid = threadIdx.x >> 6, lane = threadIdx.x & 63;
  int node = blockIdx.x * 4 + wid;
  if (node >= n) return;
  float a0 = att[2 * lane], a1 = att[2 * lane + 1];
  unsigned int xrp = xr32[(size_t)node * 64 + lane];
  float xr0 = b2f((unsigned short)xrp);
  float xr1 = b2f((unsigned short)(xrp >> 16));
  float num0 = 0.f, num1 = 0.f, den = 0.f;
  int beg = off[node], end = off[node + 1];

  auto comp = [&](unsigned int g) {
    float x0 = b2f((unsigned short)g), x1 = b2f((unsigned short)(g >> 16));
    float m0 = x0 + xr0, m1 = x1 + xr1;
    float l0 = fmaxf(m0, 0.2f * m0), l1 = fmaxf(m1, 0.2f * m1);
    float p = fmaf(l1, a1, l0 * a0);
    #pragma unroll
    for (int mask = 1; mask < 16; mask <<= 1) p += __shfl_xor(p, mask, 64);
    float wgt = __expf(p);
    num0 = fmaf(wgt, x0, num0);
    num1 = fmaf(wgt, x1, num1);
    den += wgt;
  };

  comp(xl32[(size_t)node * 64 + lane]);  // self loop
  for (int base = beg; base < end; base += 64) {
    int cnt = end - base;
    if (cnt > 64) cnt = 64;
    int my = csr[base + (lane < cnt ? lane : 0)];
    int i = 0;
    for (; i + 4 <= cnt; i += 4) {
      int s0 = __builtin_amdgcn_readlane(my, i);
      int s1 = __builtin_amdgcn_readlane(my, i + 1);
      int s2 = __builtin_amdgcn_readlane(my, i + 2);
      int s3 = __builtin_amdgcn_readlane(my, i + 3);
      unsigned int g0 = xl32[(size_t)s0 * 64 + lane];
      unsigned int g1 = xl32[(size_t)s1 * 64 + lane];
      unsigned int g2 = xl32[(size_t)s2 * 64 + lane];
      unsigned int g3 = xl32[(size_t)s3 * 64 + lane];
      comp(g0); comp(g1); comp(g2); comp(g3);
    }
    for (; i < cnt; ++i) {
      int s0 = __builtin_amdgcn_readlane(my, i);
      comp(xl32[(size_t)s0 * 64 + lane]);
    }
  }
  float inv = 1.f / (den + 1e-16f);
  float v0 = num0 * inv + bias[2 * lane];
  float v1 = num1 * inv + bias[2 * lane + 1];
  fout[(size_t)node * 64 + lane] = (unsigned)f2b(sigm(v0)) | ((unsigned)f2b(sigm(v1)) << 16);
}

// ---------------------------------------------------------------------------
// Fused GRU GEMMs.  Block 64 rows, 4 waves.  LDS 64 KB -> 2 blocks/CU.
// Phase1 (N=256): wave w owns cols {w*32..+31} U {128+w*32..+31} so the
// u-gate fragment layout matches phase2's accumulator -> u stays in VGPRs.
// B chunks register-prefetched (issue-early / write-late).
// ---------------------------------------------------------------------------
__global__ __launch_bounds__(256) void gemm_fused(const unsigned short* __restrict__ fbuf,
                                                  const float* __restrict__ hf,
                                                  const unsigned short* __restrict__ Bt1,
                                                  const unsigned short* __restrict__ Bt2,
                                                  const float* __restrict__ b1,
                                                  const float* __restrict__ b2,
                                                  float* __restrict__ out, int n) {
  __shared__ char As[64 * 512];           // [f|h] 64 rows x 256 bf16, 32 KB
  __shared__ char Bs[256 * 128];          // B K-chunk, 32 KB
  int t = threadIdx.x;
  int w = t >> 6, l = t & 63;
  int row0 = blockIdx.x * 64;
  int l15 = l & 15, lhi = l >> 4;

  // stage A = [f | h]: src linear, dest swizzled
  #pragma unroll
  for (int u_ = 0; u_ < 8; ++u_) {
    int unit = t + u_ * 256;
    int r = unit >> 5, slot = unit & 31;
    int koff = slot * 16;
    int grow = row0 + r;
    uint4 v = make_uint4(0, 0, 0, 0);
    if (grow < n) {
      if (koff < 256) {
        v = *(const uint4*)(fbuf + (size_t)grow * 128 + koff / 2);
      } else {
        const float* s = hf + (size_t)grow * 128 + (koff - 256) / 2;
        float4 f0 = *(const float4*)s, f1 = *(const float4*)(s + 4);
        v.x = (unsigned)f2b(f0.x) | ((unsigned)f2b(f0.y) << 16);
        v.y = (unsigned)f2b(f0.z) | ((unsigned)f2b(f0.w) << 16);
        v.z = (unsigned)f2b(f1.x) | ((unsigned)f2b(f1.y) << 16);
        v.w = (unsigned)f2b(f1.z) | ((unsigned)f2b(f1.w) << 16);
      }
    }
    *(uint4*)(As + r * 512 + (koff ^ ((r & 7) << 4))) = v;
  }

  // ---- phase 1: K=256, N=256 ----
  floatx4 acc[4][4];
  #pragma unroll
  for (int mt = 0; mt < 4; ++mt)
    #pragma unroll
    for (int nt = 0; nt < 4; ++nt) acc[mt][nt] = (floatx4){0.f, 0.f, 0.f, 0.f};

  uint4 breg[8];
  #pragma unroll
  for (int u_ = 0; u_ < 8; ++u_) {        // prefetch ks=0
    int unit = t + u_ * 256;
    int r = unit >> 3, b16 = unit & 7;
    breg[u_] = *(const uint4*)(Bt1 + (size_t)r * 256 + b16 * 8);
  }

  for (int ks = 0; ks < 4; ++ks) {
    #pragma unroll
    for (int u_ = 0; u_ < 8; ++u_) {      // write-late into Bs (swizzled)
      int unit = t + u_ * 256;
      int r = unit >> 3, b16 = unit & 7;
      *(uint4*)(Bs + r * 128 + ((b16 * 16) ^ ((r & 7) << 4))) = breg[u_];
    }
    __syncthreads();
    if (ks < 3) {                          // issue-early next chunk
      #pragma unroll
      for (int u_ = 0; u_ < 8; ++u_) {
        int unit = t + u_ * 256;
        int r = unit >> 3, b16 = unit & 7;
        breg[u_] = *(const uint4*)(Bt1 + (size_t)r * 256 + (ks + 1) * 64 + b16 * 8);
      }
    }
    #pragma unroll
    for (int kk = 0; kk < 2; ++kk) {
      int ka = ks * 128 + kk * 64 + lhi * 16;
      int kb = kk * 64 + lhi * 16;
      short8 a[4];
      #pragma unroll
      for (int mt = 0; mt < 4; ++mt) {
        int r = mt * 16 + l15;
        a[mt] = *(const short8*)(As + r * 512 + (ka ^ ((r & 7) << 4)));
      }
      #pragma unroll
      for (int nt = 0; nt < 4; ++nt) {
        int r = ((nt < 2) ? (w * 32 + nt * 16) : (128 + w * 32 + (nt - 2) * 16)) + l15;
        short8 b = *(const short8*)(Bs + r * 128 + (kb ^ ((r & 7) << 4)));
        #pragma unroll
        for (int mt = 0; mt < 4; ++mt)
          acc[mt][nt] = __builtin_amdgcn_mfma_f32_16x16x32_bf16(a[mt], b, acc[mt][nt], 0, 0, 0);
      }
    }
    __syncthreads();
  }

  // phase-1 epilogue: r-cols -> rh overwrites h half of As (swizzled);
  // u-cols stay in registers (layout matches phase-2 accumulator).
  float us[4][2][4];
  #pragma unroll
  for (int mt = 0; mt < 4; ++mt)
    #pragma unroll
    for (int nt = 0; nt < 4; ++nt) {
      #pragma unroll
      for (int j = 0; j < 4; ++j) {
        int rloc = mt * 16 + lhi * 4 + j;
        if (nt < 2) {
          int col = w * 32 + nt * 16 + l15;
          float s = sigm(acc[mt][nt][j] + b1[col]);
          int byteoff = (256 + col * 2) ^ ((rloc & 7) << 4);
          char* p = As + rloc * 512 + byteoff;
          unsigned short hv = *(unsigned short*)p;
          *(unsigned short*)p = f2b(s * b2f(hv));
        } else {
          int col = 128 + w * 32 + (nt - 2) * 16 + l15;
          us[mt][nt - 2][j] = sigm(acc[mt][nt][j] + b1[col]);
        }
      }
    }
  __syncthreads();

  // ---- phase 2: K=256, N=128; wave w owns cols w*32..+31 ----
  floatx4 acc2[4][2];
  #pragma unroll
  for (int mt = 0; mt < 4; ++mt)
    #pragma unroll
    for (int nt = 0; nt < 2; ++nt) acc2[mt][nt] = (floatx4){0.f, 0.f, 0.f, 0.f};

  uint4 breg2[4];
  #pragma unroll
  for (int u_ = 0; u_ < 4; ++u_) {         // prefetch ks=0
    int unit = t + u_ * 256;
    int r = unit >> 3, b16 = unit & 7;
    breg2[u_] = *(const uint4*)(Bt2 + (size_t)r * 256 + b16 * 8);
  }

  for (int ks = 0; ks < 4; ++ks) {
    #pragma unroll
    for (int u_ = 0; u_ < 4; ++u_) {
      int unit = t + u_ * 256;
      int r = unit >> 3, b16 = unit & 7;
      *(uint4*)(Bs + r * 128 + ((b16 * 16) ^ ((r & 7) << 4))) = breg2[u_];
    }
    __syncthreads();
    if (ks < 3) {
      #pragma unroll
      for (int u_ = 0; u_ < 4; ++u_) {
        int unit = t + u_ * 256;
        int r = unit >> 3, b16 = unit & 7;
        breg2[u_] = *(const uint4*)(Bt2 + (size_t)r * 256 + (ks + 1) * 64 + b16 * 8);
      }
    }
    #pragma unroll
    for (int kk = 0; kk < 2; ++kk) {
      int ka = ks * 128 + kk * 64 + lhi * 16;
      int kb = kk * 64 + lhi * 16;
      short8 a[4];
      #pragma unroll
      for (int mt = 0; mt < 4; ++mt) {
        int r = mt * 16 + l15;
        a[mt] = *(const short8*)(As + r * 512 + (ka ^ ((r & 7) << 4)));
      }
      #pragma unroll
      for (int nt = 0; nt < 2; ++nt) {
        int r = w * 32 + nt * 16 + l15;
        short8 b = *(const short8*)(Bs + r * 128 + (kb ^ ((r & 7) << 4)));
        #pragma unroll
        for (int mt = 0; mt < 4; ++mt)
          acc2[mt][nt] = __builtin_amdgcn_mfma_f32_16x16x32_bf16(a[mt], b, acc2[mt][nt], 0, 0, 0);
      }
    }
    __syncthreads();
  }

  #pragma unroll
  for (int mt = 0; mt < 4; ++mt)
    #pragma unroll
    for (int nt = 0; nt < 2; ++nt) {
      int col = w * 32 + nt * 16 + l15;
      #pragma unroll
      for (int j = 0; j < 4; ++j) {
        int rloc = mt * 16 + lhi * 4 + j;
        int row = row0 + rloc;
        if (row >= n) continue;
        float c = tanh_fast(acc2[mt][nt][j] + b2[col]);
        float uu = us[mt][nt][j];
        float hv = hf[(size_t)row * 128 + col];
        out[(size_t)row * 128 + col] = uu * hv + (1.f - uu) * c;
      }
    }
}

extern "C" void kernel_launch(void* const* d_in, const int* in_sizes, int n_in,
                              void* d_out, int out_size, void* d_ws, size_t ws_size,
                              hipStream_t stream) {
  const float* x     = (const float*)d_in[0];
  const void*  ei    = d_in[1];
  const float* h     = (const float*)d_in[3];
  const float* Wl    = (const float*)d_in[4];
  const float* Wr    = (const float*)d_in[5];
  const float* att   = (const float*)d_in[6];
  const float* bconv = (const float*)d_in[7];
  const float* W1    = (const float*)d_in[8];
  const float* b1    = (const float*)d_in[9];
  const float* W2    = (const float*)d_in[10];
  const float* b2    = (const float*)d_in[11];
  float* out = (float*)d_out;

  const int n = in_sizes[0] / 128;   // 50000
  const int E = in_sizes[1] / 2;     // 800000

  char* w = (char*)d_ws;
  size_t o = 0;
  auto alloc = [&](size_t bytes) {
    char* p = w + o;
    o += bytes;
    o = (o + 255) & ~(size_t)255;
    return p;
  };
  int* flag   = (int*)alloc(4);
  int* deg    = (int*)alloc((size_t)(n + 1) * 4);
  int* off    = (int*)alloc((size_t)(n + 1) * 4);
  int* cursor = (int*)alloc((size_t)(n + 1) * 4);
  int* bsum   = (int*)alloc(1024 * 4);
  int* csr    = (int*)alloc((size_t)E * 4);
  unsigned short* xl   = (unsigned short*)alloc((size_t)n * 128 * 2);
  unsigned short* xr   = (unsigned short*)alloc((size_t)n * 128 * 2);
  unsigned short* fbuf = (unsigned short*)alloc((size_t)n * 128 * 2);
  unsigned short* Btxw = (unsigned short*)alloc(256 * 128 * 2);
  unsigned short* Bt1  = (unsigned short*)alloc(256 * 256 * 2);
  unsigned short* Bt2  = (unsigned short*)alloc(128 * 256 * 2);

  hipMemsetAsync(deg, 0, (size_t)(n + 1) * 4, stream);
  detect_kernel<<<1, 1024, 0, stream>>>((const unsigned int*)ei, 2LL * E, flag);
  hist_kernel<<<(E + 255) / 256, 256, 0, stream>>>(ei, E, flag, deg);
  int nb = (n + 1023) / 1024;
  scan_partial<<<nb, 256, 0, stream>>>(deg, bsum, n);
  scan_bsums<<<1, 64, 0, stream>>>(bsum, nb);
  scan_final<<<nb, 256, 0, stream>>>(deg, bsum, off, cursor, n);
  scatter_kernel<<<(E + 255) / 256, 256, 0, stream>>>(ei, E, flag, cursor, csr);
  wprep<<<512, 256, 0, stream>>>(Wl, Wr, W1, W2, Btxw, Bt1, Bt2);

  int gblocks = (n + 63) / 64;
  gemm_xw<<<gblocks, 256, 0, stream>>>(x, Btxw, xl, xr, n);
  node_kernel<<<(n + 3) / 4, 256, 0, stream>>>((const unsigned int*)xl, (const unsigned int*)xr,
                                               att, bconv, off, csr,
                                               (unsigned int*)fbuf, n);
  gemm_fused<<<gblocks, 256, 0, stream>>>(fbuf, h, Bt1, Bt2, b1, b2, out, n);
}

// Round 8
// 223.840 us; speedup vs baseline: 1.2004x; 1.2004x over previous
//
#include <hip/hip_runtime.h>
#include <hip/hip_bf16.h>
#include <math.h>

typedef __attribute__((ext_vector_type(8))) short short8;
typedef __attribute__((ext_vector_type(4))) float floatx4;

__device__ __forceinline__ unsigned short f2b(float f) {
  unsigned int u = __builtin_bit_cast(unsigned int, f);
  u += 0x7fffu + ((u >> 16) & 1u);
  return (unsigned short)(u >> 16);
}
__device__ __forceinline__ float b2f(unsigned short s) {
  unsigned int u = ((unsigned int)s) << 16;
  return __builtin_bit_cast(float, u);
}
__device__ __forceinline__ float sigm(float v) { return 1.f / (1.f + __expf(-v)); }
__device__ __forceinline__ float tanh_fast(float y) {
  float t = __expf(2.f * y);
  return 1.f - 2.f / (t + 1.f);
}

// ---------------------------------------------------------------------------
// Edge preprocessing
// ---------------------------------------------------------------------------
__global__ __launch_bounds__(1024) void detect_kernel(const unsigned int* __restrict__ ei,
                                                      long long n_u32, int* __restrict__ flag) {
  __shared__ int any;
  if (threadIdx.x == 0) any = 0;
  __syncthreads();
  int nz = 0;
  for (int rep = 0; rep < 4; ++rep) {
    long long idx = 2LL * (threadIdx.x + rep * 1024) + 1;
    if (idx < n_u32 && ei[idx] != 0u) nz = 1;
  }
  if (nz) atomicOr(&any, 1);
  __syncthreads();
  if (threadIdx.x == 0) *flag = any;  // 1 -> int32 data, 0 -> int64 data
}

__device__ __forceinline__ void load_edge(const void* ei, int E, int flag, int i,
                                          int& s, int& d) {
  if (flag == 0) {
    const long long* p = (const long long*)ei;
    s = (int)p[i];
    d = (int)p[(long long)E + i];
  } else {
    const int* p = (const int*)ei;
    s = p[i];
    d = p[E + i];
  }
}

__global__ __launch_bounds__(256) void hist_kernel(const void* __restrict__ ei, int E,
                                                   const int* __restrict__ flag,
                                                   int* __restrict__ deg) {
  int i = blockIdx.x * 256 + threadIdx.x;
  if (i >= E) return;
  int s, d;
  load_edge(ei, E, *flag, i, s, d);
  atomicAdd(&deg[d], 1);
}

// parallel scan, 3 kernels
__global__ __launch_bounds__(256) void scan_partial(const int* __restrict__ deg,
                                                    int* __restrict__ bsum, int n) {
  __shared__ int ws[4];
  int base = blockIdx.x * 1024 + threadIdx.x * 4;
  int lane = threadIdx.x & 63, wid = threadIdx.x >> 6;
  int tot = 0;
  #pragma unroll
  for (int k = 0; k < 4; ++k) {
    int i = base + k;
    if (i < n) tot += deg[i];
  }
  #pragma unroll
  for (int ofs = 1; ofs < 64; ofs <<= 1) tot += __shfl_xor(tot, ofs, 64);
  if (lane == 0) ws[wid] = tot;
  __syncthreads();
  if (threadIdx.x == 0) bsum[blockIdx.x] = ws[0] + ws[1] + ws[2] + ws[3];
}

__global__ __launch_bounds__(64) void scan_bsums(int* __restrict__ bsum, int nb) {
  int lane = threadIdx.x;
  int carry = 0;
  for (int base = 0; base < nb; base += 64) {
    int i = base + lane;
    int v = (i < nb) ? bsum[i] : 0;
    int s = v;
    #pragma unroll
    for (int ofs = 1; ofs < 64; ofs <<= 1) {
      int t = __shfl_up(s, ofs, 64);
      if (lane >= ofs) s += t;
    }
    if (i < nb) bsum[i] = s - v + carry;           // exclusive
    int tot = __shfl(s, 63, 64);
    carry += tot;
  }
}

__global__ __launch_bounds__(256) void scan_final(const int* __restrict__ deg,
                                                  const int* __restrict__ bsum,
                                                  int* __restrict__ off,
                                                  int* __restrict__ cursor, int n) {
  __shared__ int ws[4];
  int lane = threadIdx.x & 63, wid = threadIdx.x >> 6;
  int base = blockIdx.x * 1024 + threadIdx.x * 4;
  int v[4];
  int tot = 0;
  #pragma unroll
  for (int k = 0; k < 4; ++k) {
    int i = base + k;
    v[k] = (i < n) ? deg[i] : 0;
    tot += v[k];
  }
  int s = tot;
  #pragma unroll
  for (int ofs = 1; ofs < 64; ofs <<= 1) {
    int t = __shfl_up(s, ofs, 64);
    if (lane >= ofs) s += t;
  }
  if (lane == 63) ws[wid] = s;
  __syncthreads();
  int wpre = 0;
  for (int ww = 0; ww < wid; ++ww) wpre += ws[ww];
  int p = bsum[blockIdx.x] + wpre + (s - tot);
  if (blockIdx.x == 0 && threadIdx.x == 0) { off[0] = 0; cursor[0] = 0; }
  #pragma unroll
  for (int k = 0; k < 4; ++k) {
    int i = base + k;
    p += v[k];
    if (i < n) { off[i + 1] = p; cursor[i + 1] = p; }
  }
}

__global__ __launch_bounds__(256) void scatter_kernel(const void* __restrict__ ei, int E,
                                                      const int* __restrict__ flag,
                                                      int* __restrict__ cursor,
                                                      int* __restrict__ csr) {
  int i = blockIdx.x * 256 + threadIdx.x;
  if (i >= E) return;
  int s, d;
  load_edge(ei, E, *flag, i, s, d);
  int pos = atomicAdd(&cursor[d], 1);
  csr[pos] = s;
}

// ---------------------------------------------------------------------------
// Weights -> bf16 in MFMA FRAGMENT ORDER.  Frag = 64 lanes x short8 (1 KB),
// lane l: col = colbase + (l&15), k = kbase + (l>>4)*8 .. +8.
//   Btfxw: fid=(w*4+nt)*4+kk          col=w*64+nt*16      k=kk*32      (4096)
//   Btf1:  fid=((w*4+nt)*4+ks)*2+kk   col=map(w,nt)       k=ks*64+kk*32 (8192)
//   Btf2:  fid=((w*2+nt)*4+ks)*2+kk   col=w*32+nt*16      k=ks*64+kk*32 (4096)
// ---------------------------------------------------------------------------
__global__ __launch_bounds__(256) void wprep(const float* __restrict__ Wl,
                                             const float* __restrict__ Wr,
                                             const float* __restrict__ W1,
                                             const float* __restrict__ W2,
                                             unsigned short* __restrict__ Btfxw,
                                             unsigned short* __restrict__ Btf1,
                                             unsigned short* __restrict__ Btf2) {
  int gid = blockIdx.x * 256 + threadIdx.x;   // 16384 total, one short8 group each
  if (gid < 4096) {                           // xw
    int lane = gid & 63, fid = gid >> 6;
    int l15 = lane & 15, lhi = lane >> 4;
    int kk = fid & 3, nt = (fid >> 2) & 3, w = fid >> 4;
    int col = w * 64 + nt * 16 + l15;
    int k0 = kk * 32 + lhi * 8;
    #pragma unroll
    for (int e = 0; e < 8; ++e) {
      float v = (col < 128) ? Wl[(k0 + e) * 128 + col] : Wr[(k0 + e) * 128 + (col - 128)];
      Btfxw[(size_t)gid * 8 + e] = f2b(v);
    }
  } else if (gid < 12288) {                   // W1
    int g = gid - 4096;
    int lane = g & 63, fid = g >> 6;
    int l15 = lane & 15, lhi = lane >> 4;
    int kk = fid & 1, ks = (fid >> 1) & 3, nt = (fid >> 3) & 3, w = fid >> 5;
    int col = (nt < 2) ? (w * 32 + nt * 16 + l15) : (128 + w * 32 + (nt - 2) * 16 + l15);
    int k0 = ks * 64 + kk * 32 + lhi * 8;
    #pragma unroll
    for (int e = 0; e < 8; ++e)
      Btf1[(size_t)g * 8 + e] = f2b(W1[(k0 + e) * 256 + col]);
  } else {                                    // W2
    int g = gid - 12288;
    int lane = g & 63, fid = g >> 6;
    int l15 = lane & 15, lhi = lane >> 4;
    int kk = fid & 1, ks = (fid >> 1) & 3, nt = (fid >> 3) & 1, w = fid >> 4;
    int col = w * 32 + nt * 16 + l15;
    int k0 = ks * 64 + kk * 32 + lhi * 8;
    #pragma unroll
    for (int e = 0; e < 8; ++e)
      Btf2[(size_t)g * 8 + e] = f2b(W2[(k0 + e) * 128 + col]);
  }
}

// ---------------------------------------------------------------------------
// xl|xr = x @ [Wl|Wr].  LDS = A only (16 KB).  One barrier.  B from global
// fragments (L2-resident).  Wave w: cols w*64..+63.
// ---------------------------------------------------------------------------
__global__ __launch_bounds__(256) void gemm_xw(const float* __restrict__ x,
                                               const unsigned short* __restrict__ Btf,
                                               unsigned short* __restrict__ xl,
                                               unsigned short* __restrict__ xr, int n) {
  __shared__ char As[64 * 256];    // 64 rows x 128 bf16, swizzled
  int t = threadIdx.x;
  int w = t >> 6, l = t & 63;
  int row0 = blockIdx.x * 64;
  int l15 = l & 15, lhi = l >> 4;

  // stage A from f32: src linear, dest swizzled (rule #21)
  #pragma unroll
  for (int u_ = 0; u_ < 4; ++u_) {
    int unit = t + u_ * 256;
    int r = unit >> 4, slot = unit & 15;
    int grow = row0 + r;
    uint4 o = make_uint4(0, 0, 0, 0);
    if (grow < n) {
      const float* s = x + (size_t)grow * 128 + slot * 8;
      float4 f0 = *(const float4*)s, f1 = *(const float4*)(s + 4);
      o.x = (unsigned)f2b(f0.x) | ((unsigned)f2b(f0.y) << 16);
      o.y = (unsigned)f2b(f0.z) | ((unsigned)f2b(f0.w) << 16);
      o.z = (unsigned)f2b(f1.x) | ((unsigned)f2b(f1.y) << 16);
      o.w = (unsigned)f2b(f1.z) | ((unsigned)f2b(f1.w) << 16);
    }
    *(uint4*)(As + r * 256 + ((slot * 16) ^ ((r & 7) << 4))) = o;
  }
  __syncthreads();

  floatx4 acc[4][4];
  #pragma unroll
  for (int mt = 0; mt < 4; ++mt)
    #pragma unroll
    for (int nt = 0; nt < 4; ++nt) acc[mt][nt] = (floatx4){0.f, 0.f, 0.f, 0.f};

  #pragma unroll 1
  for (int kk = 0; kk < 4; ++kk) {
    int ko = kk * 64 + lhi * 16;
    short8 a[4];
    #pragma unroll
    for (int mt = 0; mt < 4; ++mt) {
      int r = mt * 16 + l15;
      a[mt] = *(const short8*)(As + r * 256 + (ko ^ ((r & 7) << 4)));
    }
    short8 b[4];
    #pragma unroll
    for (int nt = 0; nt < 4; ++nt) {
      int fid = (w * 4 + nt) * 4 + kk;
      b[nt] = *(const short8*)(Btf + ((size_t)fid * 64 + l) * 8);
    }
    #pragma unroll
    for (int nt = 0; nt < 4; ++nt)
      #pragma unroll
      for (int mt = 0; mt < 4; ++mt)
        acc[mt][nt] = __builtin_amdgcn_mfma_f32_16x16x32_bf16(a[mt], b[nt], acc[mt][nt], 0, 0, 0);
  }

  #pragma unroll
  for (int mt = 0; mt < 4; ++mt)
    #pragma unroll
    for (int nt = 0; nt < 4; ++nt) {
      int col = w * 64 + nt * 16 + l15;
      int rbase = row0 + mt * 16 + lhi * 4;
      #pragma unroll
      for (int j = 0; j < 4; ++j) {
        int row = rbase + j;
        if (row >= n) continue;
        unsigned short v = f2b(acc[mt][nt][j]);
        if (col < 128) xl[(size_t)row * 128 + col] = v;
        else           xr[(size_t)row * 128 + (col - 128)] = v;
      }
    }
}

// ---------------------------------------------------------------------------
// One wave per node; lane l owns dims (2l, 2l+1); head = l>>4.
// ---------------------------------------------------------------------------
__global__ __launch_bounds__(256) void node_kernel(const unsigned int* __restrict__ xl32,
                                                   const unsigned int* __restrict__ xr32,
                                                   const float* __restrict__ att,
                                                   const float* __restrict__ bias,
                                                   const int* __restrict__ off,
                                                   const int* __restrict__ csr,
                                                   unsigned int* __restrict__ fout, int n) {
  int wid = threadIdx.x >> 6, lane = threadIdx.x & 63;
  int node = blockIdx.x * 4 + wid;
  if (node >= n) return;
  float a0 = att[2 * lane], a1 = att[2 * lane + 1];
  unsigned int xrp = xr32[(size_t)node * 64 + lane];
  float xr0 = b2f((unsigned short)xrp);
  float xr1 = b2f((unsigned short)(xrp >> 16));
  float num0 = 0.f, num1 = 0.f, den = 0.f;
  int beg = off[node], end = off[node + 1];

  auto comp = [&](unsigned int g) {
    float x0 = b2f((unsigned short)g), x1 = b2f((unsigned short)(g >> 16));
    float m0 = x0 + xr0, m1 = x1 + xr1;
    float l0 = fmaxf(m0, 0.2f * m0), l1 = fmaxf(m1, 0.2f * m1);
    float p = fmaf(l1, a1, l0 * a0);
    #pragma unroll
    for (int mask = 1; mask < 16; mask <<= 1) p += __shfl_xor(p, mask, 64);
    float wgt = __expf(p);
    num0 = fmaf(wgt, x0, num0);
    num1 = fmaf(wgt, x1, num1);
    den += wgt;
  };

  comp(xl32[(size_t)node * 64 + lane]);  // self loop
  for (int base = beg; base < end; base += 64) {
    int cnt = end - base;
    if (cnt > 64) cnt = 64;
    int my = csr[base + (lane < cnt ? lane : 0)];
    int i = 0;
    for (; i + 4 <= cnt; i += 4) {
      int s0 = __builtin_amdgcn_readlane(my, i);
      int s1 = __builtin_amdgcn_readlane(my, i + 1);
      int s2 = __builtin_amdgcn_readlane(my, i + 2);
      int s3 = __builtin_amdgcn_readlane(my, i + 3);
      unsigned int g0 = xl32[(size_t)s0 * 64 + lane];
      unsigned int g1 = xl32[(size_t)s1 * 64 + lane];
      unsigned int g2 = xl32[(size_t)s2 * 64 + lane];
      unsigned int g3 = xl32[(size_t)s3 * 64 + lane];
      comp(g0); comp(g1); comp(g2); comp(g3);
    }
    for (; i < cnt; ++i) {
      int s0 = __builtin_amdgcn_readlane(my, i);
      comp(xl32[(size_t)s0 * 64 + lane]);
    }
  }
  float inv = 1.f / (den + 1e-16f);
  float v0 = num0 * inv + bias[2 * lane];
  float v1 = num1 * inv + bias[2 * lane + 1];
  fout[(size_t)node * 64 + lane] = (unsigned)f2b(sigm(v0)) | ((unsigned)f2b(sigm(v1)) << 16);
}

// ---------------------------------------------------------------------------
// Fused GRU GEMMs.  LDS = A only (32 KB).  B from global fragments.
// Phase1 wave w: cols {w*32..} U {128+w*32..} -> u gate stays in registers.
// RACE FIX (r7): __syncthreads() between phase-1 reads of As and the
// epilogue's in-place h->rh overwrite of As.
// ---------------------------------------------------------------------------
__global__ __launch_bounds__(256) void gemm_fused(const unsigned short* __restrict__ fbuf,
                                                  const float* __restrict__ hf,
                                                  const unsigned short* __restrict__ Btf1,
                                                  const unsigned short* __restrict__ Btf2,
                                                  const float* __restrict__ b1,
                                                  const float* __restrict__ b2,
                                                  float* __restrict__ out, int n) {
  __shared__ char As[64 * 512];           // [f|h] 64 rows x 256 bf16, swizzled
  int t = threadIdx.x;
  int w = t >> 6, l = t & 63;
  int row0 = blockIdx.x * 64;
  int l15 = l & 15, lhi = l >> 4;

  // stage A = [f | h]: src linear, dest swizzled
  #pragma unroll
  for (int u_ = 0; u_ < 8; ++u_) {
    int unit = t + u_ * 256;
    int r = unit >> 5, slot = unit & 31;
    int koff = slot * 16;
    int grow = row0 + r;
    uint4 v = make_uint4(0, 0, 0, 0);
    if (grow < n) {
      if (koff < 256) {
        v = *(const uint4*)(fbuf + (size_t)grow * 128 + koff / 2);
      } else {
        const float* s = hf + (size_t)grow * 128 + (koff - 256) / 2;
        float4 f0 = *(const float4*)s, f1 = *(const float4*)(s + 4);
        v.x = (unsigned)f2b(f0.x) | ((unsigned)f2b(f0.y) << 16);
        v.y = (unsigned)f2b(f0.z) | ((unsigned)f2b(f0.w) << 16);
        v.z = (unsigned)f2b(f1.x) | ((unsigned)f2b(f1.y) << 16);
        v.w = (unsigned)f2b(f1.z) | ((unsigned)f2b(f1.w) << 16);
      }
    }
    *(uint4*)(As + r * 512 + (koff ^ ((r & 7) << 4))) = v;
  }
  __syncthreads();

  // ---- phase 1: K=256, N=256 ----
  floatx4 acc[4][4];
  #pragma unroll
  for (int mt = 0; mt < 4; ++mt)
    #pragma unroll
    for (int nt = 0; nt < 4; ++nt) acc[mt][nt] = (floatx4){0.f, 0.f, 0.f, 0.f};

  #pragma unroll 1
  for (int ks = 0; ks < 4; ++ks) {
    #pragma unroll
    for (int kk = 0; kk < 2; ++kk) {
      int ka = ks * 128 + kk * 64 + lhi * 16;
      short8 a[4];
      #pragma unroll
      for (int mt = 0; mt < 4; ++mt) {
        int r = mt * 16 + l15;
        a[mt] = *(const short8*)(As + r * 512 + (ka ^ ((r & 7) << 4)));
      }
      #pragma unroll
      for (int nt = 0; nt < 4; ++nt) {
        int fid = ((w * 4 + nt) * 4 + ks) * 2 + kk;
        short8 b = *(const short8*)(Btf1 + ((size_t)fid * 64 + l) * 8);
        #pragma unroll
        for (int mt = 0; mt < 4; ++mt)
          acc[mt][nt] = __builtin_amdgcn_mfma_f32_16x16x32_bf16(a[mt], b, acc[mt][nt], 0, 0, 0);
      }
    }
  }
  __syncthreads();   // RACE FIX: all waves done reading As (h half) before overwrite

  // phase-1 epilogue: r-cols -> rh overwrites h half of As (swizzled);
  // u-cols stay in registers (layout matches phase-2 accumulator).
  float us[4][2][4];
  #pragma unroll
  for (int mt = 0; mt < 4; ++mt)
    #pragma unroll
    for (int nt = 0; nt < 4; ++nt) {
      #pragma unroll
      for (int j = 0; j < 4; ++j) {
        int rloc = mt * 16 + lhi * 4 + j;
        if (nt < 2) {
          int col = w * 32 + nt * 16 + l15;
          float s = sigm(acc[mt][nt][j] + b1[col]);
          int byteoff = (256 + col * 2) ^ ((rloc & 7) << 4);
          char* p = As + rloc * 512 + byteoff;
          unsigned short hv = *(unsigned short*)p;
          *(unsigned short*)p = f2b(s * b2f(hv));
        } else {
          int col = 128 + w * 32 + (nt - 2) * 16 + l15;
          us[mt][nt - 2][j] = sigm(acc[mt][nt][j] + b1[col]);
        }
      }
    }
  __syncthreads();

  // ---- phase 2: K=256, N=128; wave w owns cols w*32..+31 ----
  floatx4 acc2[4][2];
  #pragma unroll
  for (int mt = 0; mt < 4; ++mt)
    #pragma unroll
    for (int nt = 0; nt < 2; ++nt) acc2[mt][nt] = (floatx4){0.f, 0.f, 0.f, 0.f};

  #pragma unroll 1
  for (int ks = 0; ks < 4; ++ks) {
    #pragma unroll
    for (int kk = 0; kk < 2; ++kk) {
      int ka = ks * 128 + kk * 64 + lhi * 16;
      short8 a[4];
      #pragma unroll
      for (int mt = 0; mt < 4; ++mt) {
        int r = mt * 16 + l15;
        a[mt] = *(const short8*)(As + r * 512 + (ka ^ ((r & 7) << 4)));
      }
      #pragma unroll
      for (int nt = 0; nt < 2; ++nt) {
        int fid = ((w * 2 + nt) * 4 + ks) * 2 + kk;
        short8 b = *(const short8*)(Btf2 + ((size_t)fid * 64 + l) * 8);
        #pragma unroll
        for (int mt = 0; mt < 4; ++mt)
          acc2[mt][nt] = __builtin_amdgcn_mfma_f32_16x16x32_bf16(a[mt], b, acc2[mt][nt], 0, 0, 0);
      }
    }
  }

  #pragma unroll
  for (int mt = 0; mt < 4; ++mt)
    #pragma unroll
    for (int nt = 0; nt < 2; ++nt) {
      int col = w * 32 + nt * 16 + l15;
      #pragma unroll
      for (int j = 0; j < 4; ++j) {
        int rloc = mt * 16 + lhi * 4 + j;
        int row = row0 + rloc;
        if (row >= n) continue;
        float c = tanh_fast(acc2[mt][nt][j] + b2[col]);
        float uu = us[mt][nt][j];
        float hv = hf[(size_t)row * 128 + col];
        out[(size_t)row * 128 + col] = uu * hv + (1.f - uu) * c;
      }
    }
}

extern "C" void kernel_launch(void* const* d_in, const int* in_sizes, int n_in,
                              void* d_out, int out_size, void* d_ws, size_t ws_size,
                              hipStream_t stream) {
  const float* x     = (const float*)d_in[0];
  const void*  ei    = d_in[1];
  const float* h     = (const float*)d_in[3];
  const float* Wl    = (const float*)d_in[4];
  const float* Wr    = (const float*)d_in[5];
  const float* att   = (const float*)d_in[6];
  const float* bconv = (const float*)d_in[7];
  const float* W1    = (const float*)d_in[8];
  const float* b1    = (const float*)d_in[9];
  const float* W2    = (const float*)d_in[10];
  const float* b2    = (const float*)d_in[11];
  float* out = (float*)d_out;

  const int n = in_sizes[0] / 128;   // 50000
  const int E = in_sizes[1] / 2;     // 800000

  char* w = (char*)d_ws;
  size_t o = 0;
  auto alloc = [&](size_t bytes) {
    char* p = w + o;
    o += bytes;
    o = (o + 255) & ~(size_t)255;
    return p;
  };
  int* flag   = (int*)alloc(4);
  int* deg    = (int*)alloc((size_t)(n + 1) * 4);
  int* off    = (int*)alloc((size_t)(n + 1) * 4);
  int* cursor = (int*)alloc((size_t)(n + 1) * 4);
  int* bsum   = (int*)alloc(1024 * 4);
  int* csr    = (int*)alloc((size_t)E * 4);
  unsigned short* xl   = (unsigned short*)alloc((size_t)n * 128 * 2);
  unsigned short* xr   = (unsigned short*)alloc((size_t)n * 128 * 2);
  unsigned short* fbuf = (unsigned short*)alloc((size_t)n * 128 * 2);
  unsigned short* Btfxw = (unsigned short*)alloc(4096 * 8 * 2);    // 64 KB
  unsigned short* Btf1  = (unsigned short*)alloc(8192 * 8 * 2);    // 128 KB
  unsigned short* Btf2  = (unsigned short*)alloc(4096 * 8 * 2);    // 64 KB

  hipMemsetAsync(deg, 0, (size_t)(n + 1) * 4, stream);
  detect_kernel<<<1, 1024, 0, stream>>>((const unsigned int*)ei, 2LL * E, flag);
  hist_kernel<<<(E + 255) / 256, 256, 0, stream>>>(ei, E, flag, deg);
  int nb = (n + 1023) / 1024;
  scan_partial<<<nb, 256, 0, stream>>>(deg, bsum, n);
  scan_bsums<<<1, 64, 0, stream>>>(bsum, nb);
  scan_final<<<nb, 256, 0, stream>>>(deg, bsum, off, cursor, n);
  scatter_kernel<<<(E + 255) / 256, 256, 0, stream>>>(ei, E, flag, cursor, csr);
  wprep<<<64, 256, 0, stream>>>(Wl, Wr, W1, W2, Btfxw, Btf1, Btf2);

  int gblocks = (n + 63) / 64;
  gemm_xw<<<gblocks, 256, 0, stream>>>(x, Btfxw, xl, xr, n);
  node_kernel<<<(n + 3) / 4, 256, 0, stream>>>((const unsigned int*)xl, (const unsigned int*)xr,
                                               att, bconv, off, csr,
                                               (unsigned int*)fbuf, n);
  gemm_fused<<<gblocks, 256, 0, stream>>>(fbuf, h, Btf1, Btf2, b1, b2, out, n);
}

// Round 9
// 164.523 us; speedup vs baseline: 1.6331x; 1.3605x over previous
//
#include <hip/hip_runtime.h>
#include <hip/hip_bf16.h>
#include <math.h>

typedef __attribute__((ext_vector_type(8))) short short8;
typedef __attribute__((ext_vector_type(4))) float floatx4;

__device__ __forceinline__ unsigned short f2b(float f) {
  unsigned int u = __builtin_bit_cast(unsigned int, f);
  u += 0x7fffu + ((u >> 16) & 1u);
  return (unsigned short)(u >> 16);
}
__device__ __forceinline__ float b2f(unsigned short s) {
  unsigned int u = ((unsigned int)s) << 16;
  return __builtin_bit_cast(float, u);
}
__device__ __forceinline__ float sigm(float v) { return 1.f / (1.f + __expf(-v)); }
__device__ __forceinline__ float tanh_fast(float y) {
  float t = __expf(2.f * y);
  return 1.f - 2.f / (t + 1.f);
}

// ---------------------------------------------------------------------------
// Edge preprocessing: dtype detect -> bucket radix partition -> CSR
// bucket = dst >> 7  (128 nodes/bucket; nbk = ceil(n/128) <= 512)
// ---------------------------------------------------------------------------
__global__ __launch_bounds__(1024) void detect_kernel(const unsigned int* __restrict__ ei,
                                                      long long n_u32, int* __restrict__ flag) {
  __shared__ int any;
  if (threadIdx.x == 0) any = 0;
  __syncthreads();
  int nz = 0;
  for (int rep = 0; rep < 4; ++rep) {
    long long idx = 2LL * (threadIdx.x + rep * 1024) + 1;
    if (idx < n_u32 && ei[idx] != 0u) nz = 1;
  }
  if (nz) atomicOr(&any, 1);
  __syncthreads();
  if (threadIdx.x == 0) *flag = any;  // 1 -> int32 data, 0 -> int64 data
}

__device__ __forceinline__ int load_dst(const void* ei, int E, int flag, int i) {
  if (flag == 0) return (int)((const long long*)ei)[(long long)E + i];
  return ((const int*)ei)[E + i];
}
__device__ __forceinline__ int load_src(const void* ei, int E, int flag, int i) {
  if (flag == 0) return (int)((const long long*)ei)[i];
  return ((const int*)ei)[i];
}

// K1: per-block LDS histogram of buckets
__global__ __launch_bounds__(256) void bucket_hist(const void* __restrict__ ei, int E,
                                                   const int* __restrict__ flag,
                                                   int* __restrict__ bucketCnt, int nbk) {
  __shared__ int h[512];
  for (int i = threadIdx.x; i < nbk; i += 256) h[i] = 0;
  __syncthreads();
  int fl = *flag;
  int gid = blockIdx.x * 256 + threadIdx.x;
  int stride = gridDim.x * 256;
  for (int i = gid; i < E; i += stride) {
    int d = load_dst(ei, E, fl, i);
    atomicAdd(&h[d >> 7], 1);
  }
  __syncthreads();
  for (int i = threadIdx.x; i < nbk; i += 256)
    if (h[i]) atomicAdd(&bucketCnt[i], h[i]);
}

// K2: 1-wave exclusive scan of bucket counts -> bucketBase (nbk+1), bucketCursor
__global__ __launch_bounds__(64) void bucket_scan(const int* __restrict__ bucketCnt,
                                                  int* __restrict__ bucketBase,
                                                  int* __restrict__ bucketCursor, int nbk) {
  int lane = threadIdx.x;
  int carry = 0;
  for (int base = 0; base < nbk; base += 64) {
    int i = base + lane;
    int v = (i < nbk) ? bucketCnt[i] : 0;
    int s = v;
    #pragma unroll
    for (int ofs = 1; ofs < 64; ofs <<= 1) {
      int t = __shfl_up(s, ofs, 64);
      if (lane >= ofs) s += t;
    }
    if (i < nbk) {
      int ex = s - v + carry;
      bucketBase[i] = ex;
      bucketCursor[i] = ex;
    }
    carry += __shfl(s, 63, 64);
  }
  if (lane == 0) bucketBase[nbk] = carry;   // == E
}

// K3: partition edges into contiguous bucket regions of pairBuf (u64 = d<<32|s)
__global__ __launch_bounds__(256) void partition_kernel(const void* __restrict__ ei, int E,
                                                        const int* __restrict__ flag,
                                                        int* __restrict__ bucketCursor,
                                                        unsigned long long* __restrict__ pairBuf,
                                                        int nbk) {
  __shared__ int h[512];
  __shared__ int base[512];
  int tid = threadIdx.x;
  for (int i = tid; i < nbk; i += 256) h[i] = 0;
  __syncthreads();
  int fl = *flag;
  int tile0 = blockIdx.x * 4096;
  int sarr[16], darr[16], rank[16];
  #pragma unroll
  for (int k = 0; k < 16; ++k) {
    int idx = tile0 + tid + k * 256;
    rank[k] = -1;
    if (idx < E) {
      sarr[k] = load_src(ei, E, fl, idx);
      darr[k] = load_dst(ei, E, fl, idx);
      rank[k] = atomicAdd(&h[darr[k] >> 7], 1);
    }
  }
  __syncthreads();
  for (int i = tid; i < nbk; i += 256)
    base[i] = h[i] ? atomicAdd(&bucketCursor[i], h[i]) : 0;
  __syncthreads();
  #pragma unroll
  for (int k = 0; k < 16; ++k) {
    if (rank[k] >= 0) {
      int bk = darr[k] >> 7;
      pairBuf[(size_t)base[bk] + rank[k]] =
          ((unsigned long long)(unsigned)darr[k] << 32) | (unsigned)sarr[k];
    }
  }
}

// K4: one block per bucket: local count -> scan -> write off[] and csr[]
__global__ __launch_bounds__(256) void csr_build(const unsigned long long* __restrict__ pairBuf,
                                                 const int* __restrict__ bucketBase,
                                                 int* __restrict__ off, int* __restrict__ csr,
                                                 int n, int E, int nbk) {
  __shared__ int cnt[128];
  __shared__ int start[128];
  __shared__ int wtot[4];
  int bk = blockIdx.x;
  int tid = threadIdx.x;
  int lo = bucketBase[bk], hi = bucketBase[bk + 1];
  int node0 = bk << 7;
  if (tid < 128) cnt[tid] = 0;
  __syncthreads();
  // pass A: per-node counts
  for (int i = lo + tid; i < hi; i += 256) {
    int d = (int)(pairBuf[i] >> 32);
    atomicAdd(&cnt[d - node0], 1);
  }
  __syncthreads();
  // exclusive scan of cnt[0..127] (waves 0 and 1)
  {
    int v = (tid < 128) ? cnt[tid] : 0;
    int s = v;
    #pragma unroll
    for (int ofs = 1; ofs < 64; ofs <<= 1) {
      int t = __shfl_up(s, ofs, 64);
      if ((tid & 63) >= ofs) s += t;
    }
    if ((tid & 63) == 63) wtot[tid >> 6] = s;
    __syncthreads();
    if (tid < 128) {
      int pre = (tid >> 6) ? wtot[0] : 0;
      start[tid] = s - v + pre;
    }
  }
  __syncthreads();
  // write off[] for this bucket's nodes
  int nNodes = n - node0;
  if (nNodes > 128) nNodes = 128;
  if (tid < nNodes) off[node0 + tid] = lo + start[tid];
  if (bk == nbk - 1 && tid == 0) off[n] = E;
  // reset cnt as local cursors
  if (tid < 128) cnt[tid] = 0;
  __syncthreads();
  // pass B: place edges
  for (int i = lo + tid; i < hi; i += 256) {
    unsigned long long pr = pairBuf[i];
    int s = (int)(unsigned)pr;
    int ld = (int)(pr >> 32) - node0;
    int r = atomicAdd(&cnt[ld], 1);
    csr[lo + start[ld] + r] = s;
  }
}

// ---------------------------------------------------------------------------
// Weights -> bf16 in MFMA FRAGMENT ORDER.  Frag = 64 lanes x short8 (1 KB),
// lane l: col = colbase + (l&15), k = kbase + (l>>4)*8 .. +8.
// ---------------------------------------------------------------------------
__global__ __launch_bounds__(256) void wprep(const float* __restrict__ Wl,
                                             const float* __restrict__ Wr,
                                             const float* __restrict__ W1,
                                             const float* __restrict__ W2,
                                             unsigned short* __restrict__ Btfxw,
                                             unsigned short* __restrict__ Btf1,
                                             unsigned short* __restrict__ Btf2) {
  int gid = blockIdx.x * 256 + threadIdx.x;   // 16384 total
  if (gid < 4096) {                           // xw
    int lane = gid & 63, fid = gid >> 6;
    int l15 = lane & 15, lhi = lane >> 4;
    int kk = fid & 3, nt = (fid >> 2) & 3, w = fid >> 4;
    int col = w * 64 + nt * 16 + l15;
    int k0 = kk * 32 + lhi * 8;
    #pragma unroll
    for (int e = 0; e < 8; ++e) {
      float v = (col < 128) ? Wl[(k0 + e) * 128 + col] : Wr[(k0 + e) * 128 + (col - 128)];
      Btfxw[(size_t)gid * 8 + e] = f2b(v);
    }
  } else if (gid < 12288) {                   // W1
    int g = gid - 4096;
    int lane = g & 63, fid = g >> 6;
    int l15 = lane & 15, lhi = lane >> 4;
    int kk = fid & 1, ks = (fid >> 1) & 3, nt = (fid >> 3) & 3, w = fid >> 5;
    int col = (nt < 2) ? (w * 32 + nt * 16 + l15) : (128 + w * 32 + (nt - 2) * 16 + l15);
    int k0 = ks * 64 + kk * 32 + lhi * 8;
    #pragma unroll
    for (int e = 0; e < 8; ++e)
      Btf1[(size_t)g * 8 + e] = f2b(W1[(k0 + e) * 256 + col]);
  } else {                                    // W2
    int g = gid - 12288;
    int lane = g & 63, fid = g >> 6;
    int l15 = lane & 15, lhi = lane >> 4;
    int kk = fid & 1, ks = (fid >> 1) & 3, nt = (fid >> 3) & 1, w = fid >> 4;
    int col = w * 32 + nt * 16 + l15;
    int k0 = ks * 64 + kk * 32 + lhi * 8;
    #pragma unroll
    for (int e = 0; e < 8; ++e)
      Btf2[(size_t)g * 8 + e] = f2b(W2[(k0 + e) * 128 + col]);
  }
}

// ---------------------------------------------------------------------------
// xl|xr = x @ [Wl|Wr].  LDS = A only (16 KB).  One barrier.  B from global
// fragments (L2-resident).  Wave w: cols w*64..+63.
// ---------------------------------------------------------------------------
__global__ __launch_bounds__(256) void gemm_xw(const float* __restrict__ x,
                                               const unsigned short* __restrict__ Btf,
                                               unsigned short* __restrict__ xl,
                                               unsigned short* __restrict__ xr, int n) {
  __shared__ char As[64 * 256];    // 64 rows x 128 bf16, swizzled
  int t = threadIdx.x;
  int w = t >> 6, l = t & 63;
  int row0 = blockIdx.x * 64;
  int l15 = l & 15, lhi = l >> 4;

  // stage A from f32: src linear, dest swizzled (rule #21)
  #pragma unroll
  for (int u_ = 0; u_ < 4; ++u_) {
    int unit = t + u_ * 256;
    int r = unit >> 4, slot = unit & 15;
    int grow = row0 + r;
    uint4 o = make_uint4(0, 0, 0, 0);
    if (grow < n) {
      const float* s = x + (size_t)grow * 128 + slot * 8;
      float4 f0 = *(const float4*)s, f1 = *(const float4*)(s + 4);
      o.x = (unsigned)f2b(f0.x) | ((unsigned)f2b(f0.y) << 16);
      o.y = (unsigned)f2b(f0.z) | ((unsigned)f2b(f0.w) << 16);
      o.z = (unsigned)f2b(f1.x) | ((unsigned)f2b(f1.y) << 16);
      o.w = (unsigned)f2b(f1.z) | ((unsigned)f2b(f1.w) << 16);
    }
    *(uint4*)(As + r * 256 + ((slot * 16) ^ ((r & 7) << 4))) = o;
  }
  __syncthreads();

  floatx4 acc[4][4];
  #pragma unroll
  for (int mt = 0; mt < 4; ++mt)
    #pragma unroll
    for (int nt = 0; nt < 4; ++nt) acc[mt][nt] = (floatx4){0.f, 0.f, 0.f, 0.f};

  #pragma unroll 1
  for (int kk = 0; kk < 4; ++kk) {
    int ko = kk * 64 + lhi * 16;
    short8 a[4];
    #pragma unroll
    for (int mt = 0; mt < 4; ++mt) {
      int r = mt * 16 + l15;
      a[mt] = *(const short8*)(As + r * 256 + (ko ^ ((r & 7) << 4)));
    }
    short8 b[4];
    #pragma unroll
    for (int nt = 0; nt < 4; ++nt) {
      int fid = (w * 4 + nt) * 4 + kk;
      b[nt] = *(const short8*)(Btf + ((size_t)fid * 64 + l) * 8);
    }
    #pragma unroll
    for (int nt = 0; nt < 4; ++nt)
      #pragma unroll
      for (int mt = 0; mt < 4; ++mt)
        acc[mt][nt] = __builtin_amdgcn_mfma_f32_16x16x32_bf16(a[mt], b[nt], acc[mt][nt], 0, 0, 0);
  }

  #pragma unroll
  for (int mt = 0; mt < 4; ++mt)
    #pragma unroll
    for (int nt = 0; nt < 4; ++nt) {
      int col = w * 64 + nt * 16 + l15;
      int rbase = row0 + mt * 16 + lhi * 4;
      #pragma unroll
      for (int j = 0; j < 4; ++j) {
        int row = rbase + j;
        if (row >= n) continue;
        unsigned short v = f2b(acc[mt][nt][j]);
        if (col < 128) xl[(size_t)row * 128 + col] = v;
        else           xr[(size_t)row * 128 + (col - 128)] = v;
      }
    }
}

// ---------------------------------------------------------------------------
// One wave per node; lane l owns dims (2l, 2l+1); head = l>>4.
// ---------------------------------------------------------------------------
__global__ __launch_bounds__(256) void node_kernel(const unsigned int* __restrict__ xl32,
                                                   const unsigned int* __restrict__ xr32,
                                                   const float* __restrict__ att,
                                                   const float* __restrict__ bias,
                                                   const int* __restrict__ off,
                                                   const int* __restrict__ csr,
                                                   unsigned int* __restrict__ fout, int n) {
  int wid = threadIdx.x >> 6, lane = threadIdx.x & 63;
  int node = blockIdx.x * 4 + wid;
  if (node >= n) return;
  float a0 = att[2 * lane], a1 = att[2 * lane + 1];
  unsigned int xrp = xr32[(size_t)node * 64 + lane];
  float xr0 = b2f((unsigned short)xrp);
  float xr1 = b2f((unsigned short)(xrp >> 16));
  float num0 = 0.f, num1 = 0.f, den = 0.f;
  int beg = off[node], end = off[node + 1];

  auto comp = [&](unsigned int g) {
    float x0 = b2f((unsigned short)g), x1 = b2f((unsigned short)(g >> 16));
    float m0 = x0 + xr0, m1 = x1 + xr1;
    float l0 = fmaxf(m0, 0.2f * m0), l1 = fmaxf(m1, 0.2f * m1);
    float p = fmaf(l1, a1, l0 * a0);
    #pragma unroll
    for (int mask = 1; mask < 16; mask <<= 1) p += __shfl_xor(p, mask, 64);
    float wgt = __expf(p);
    num0 = fmaf(wgt, x0, num0);
    num1 = fmaf(wgt, x1, num1);
    den += wgt;
  };

  comp(xl32[(size_t)node * 64 + lane]);  // self loop
  for (int base = beg; base < end; base += 64) {
    int cnt = end - base;
    if (cnt > 64) cnt = 64;
    int my = csr[base + (lane < cnt ? lane : 0)];
    int i = 0;
    for (; i + 4 <= cnt; i += 4) {
      int s0 = __builtin_amdgcn_readlane(my, i);
      int s1 = __builtin_amdgcn_readlane(my, i + 1);
      int s2 = __builtin_amdgcn_readlane(my, i + 2);
      int s3 = __builtin_amdgcn_readlane(my, i + 3);
      unsigned int g0 = xl32[(size_t)s0 * 64 + lane];
      unsigned int g1 = xl32[(size_t)s1 * 64 + lane];
      unsigned int g2 = xl32[(size_t)s2 * 64 + lane];
      unsigned int g3 = xl32[(size_t)s3 * 64 + lane];
      comp(g0); comp(g1); comp(g2); comp(g3);
    }
    for (; i < cnt; ++i) {
      int s0 = __builtin_amdgcn_readlane(my, i);
      comp(xl32[(size_t)s0 * 64 + lane]);
    }
  }
  float inv = 1.f / (den + 1e-16f);
  float v0 = num0 * inv + bias[2 * lane];
  float v1 = num1 * inv + bias[2 * lane + 1];
  fout[(size_t)node * 64 + lane] = (unsigned)f2b(sigm(v0)) | ((unsigned)f2b(sigm(v1)) << 16);
}

// ---------------------------------------------------------------------------
// Fused GRU GEMMs.  LDS = A only (32 KB).  B from global fragments.
// Phase1 wave w: cols {w*32..} U {128+w*32..} -> u gate stays in registers.
// ---------------------------------------------------------------------------
__global__ __launch_bounds__(256) void gemm_fused(const unsigned short* __restrict__ fbuf,
                                                  const float* __restrict__ hf,
                                                  const unsigned short* __restrict__ Btf1,
                                                  const unsigned short* __restrict__ Btf2,
                                                  const float* __restrict__ b1,
                                                  const float* __restrict__ b2,
                                                  float* __restrict__ out, int n) {
  __shared__ char As[64 * 512];           // [f|h] 64 rows x 256 bf16, swizzled
  int t = threadIdx.x;
  int w = t >> 6, l = t & 63;
  int row0 = blockIdx.x * 64;
  int l15 = l & 15, lhi = l >> 4;

  // stage A = [f | h]: src linear, dest swizzled
  #pragma unroll
  for (int u_ = 0; u_ < 8; ++u_) {
    int unit = t + u_ * 256;
    int r = unit >> 5, slot = unit & 31;
    int koff = slot * 16;
    int grow = row0 + r;
    uint4 v = make_uint4(0, 0, 0, 0);
    if (grow < n) {
      if (koff < 256) {
        v = *(const uint4*)(fbuf + (size_t)grow * 128 + koff / 2);
      } else {
        const float* s = hf + (size_t)grow * 128 + (koff - 256) / 2;
        float4 f0 = *(const float4*)s, f1 = *(const float4*)(s + 4);
        v.x = (unsigned)f2b(f0.x) | ((unsigned)f2b(f0.y) << 16);
        v.y = (unsigned)f2b(f0.z) | ((unsigned)f2b(f0.w) << 16);
        v.z = (unsigned)f2b(f1.x) | ((unsigned)f2b(f1.y) << 16);
        v.w = (unsigned)f2b(f1.z) | ((unsigned)f2b(f1.w) << 16);
      }
    }
    *(uint4*)(As + r * 512 + (koff ^ ((r & 7) << 4))) = v;
  }
  __syncthreads();

  // ---- phase 1: K=256, N=256 ----
  floatx4 acc[4][4];
  #pragma unroll
  for (int mt = 0; mt < 4; ++mt)
    #pragma unroll
    for (int nt = 0; nt < 4; ++nt) acc[mt][nt] = (floatx4){0.f, 0.f, 0.f, 0.f};

  #pragma unroll 1
  for (int ks = 0; ks < 4; ++ks) {
    #pragma unroll
    for (int kk = 0; kk < 2; ++kk) {
      int ka = ks * 128 + kk * 64 + lhi * 16;
      short8 a[4];
      #pragma unroll
      for (int mt = 0; mt < 4; ++mt) {
        int r = mt * 16 + l15;
        a[mt] = *(const short8*)(As + r * 512 + (ka ^ ((r & 7) << 4)));
      }
      #pragma unroll
      for (int nt = 0; nt < 4; ++nt) {
        int fid = ((w * 4 + nt) * 4 + ks) * 2 + kk;
        short8 b = *(const short8*)(Btf1 + ((size_t)fid * 64 + l) * 8);
        #pragma unroll
        for (int mt = 0; mt < 4; ++mt)
          acc[mt][nt] = __builtin_amdgcn_mfma_f32_16x16x32_bf16(a[mt], b, acc[mt][nt], 0, 0, 0);
      }
    }
  }
  __syncthreads();   // all waves done reading As (h half) before overwrite

  // phase-1 epilogue: r-cols -> rh overwrites h half of As (swizzled);
  // u-cols stay in registers (layout matches phase-2 accumulator).
  float us[4][2][4];
  #pragma unroll
  for (int mt = 0; mt < 4; ++mt)
    #pragma unroll
    for (int nt = 0; nt < 4; ++nt) {
      #pragma unroll
      for (int j = 0; j < 4; ++j) {
        int rloc = mt * 16 + lhi * 4 + j;
        if (nt < 2) {
          int col = w * 32 + nt * 16 + l15;
          float s = sigm(acc[mt][nt][j] + b1[col]);
          int byteoff = (256 + col * 2) ^ ((rloc & 7) << 4);
          char* p = As + rloc * 512 + byteoff;
          unsigned short hv = *(unsigned short*)p;
          *(unsigned short*)p = f2b(s * b2f(hv));
        } else {
          int col = 128 + w * 32 + (nt - 2) * 16 + l15;
          us[mt][nt - 2][j] = sigm(acc[mt][nt][j] + b1[col]);
        }
      }
    }
  __syncthreads();

  // ---- phase 2: K=256, N=128; wave w owns cols w*32..+31 ----
  floatx4 acc2[4][2];
  #pragma unroll
  for (int mt = 0; mt < 4; ++mt)
    #pragma unroll
    for (int nt = 0; nt < 2; ++nt) acc2[mt][nt] = (floatx4){0.f, 0.f, 0.f, 0.f};

  #pragma unroll 1
  for (int ks = 0; ks < 4; ++ks) {
    #pragma unroll
    for (int kk = 0; kk < 2; ++kk) {
      int ka = ks * 128 + kk * 64 + lhi * 16;
      short8 a[4];
      #pragma unroll
      for (int mt = 0; mt < 4; ++mt) {
        int r = mt * 16 + l15;
        a[mt] = *(const short8*)(As + r * 512 + (ka ^ ((r & 7) << 4)));
      }
      #pragma unroll
      for (int nt = 0; nt < 2; ++nt) {
        int fid = ((w * 2 + nt) * 4 + ks) * 2 + kk;
        short8 b = *(const short8*)(Btf2 + ((size_t)fid * 64 + l) * 8);
        #pragma unroll
        for (int mt = 0; mt < 4; ++mt)
          acc2[mt][nt] = __builtin_amdgcn_mfma_f32_16x16x32_bf16(a[mt], b, acc2[mt][nt], 0, 0, 0);
      }
    }
  }

  #pragma unroll
  for (int mt = 0; mt < 4; ++mt)
    #pragma unroll
    for (int nt = 0; nt < 2; ++nt) {
      int col = w * 32 + nt * 16 + l15;
      #pragma unroll
      for (int j = 0; j < 4; ++j) {
        int rloc = mt * 16 + lhi * 4 + j;
        int row = row0 + rloc;
        if (row >= n) continue;
        float c = tanh_fast(acc2[mt][nt][j] + b2[col]);
        float uu = us[mt][nt][j];
        float hv = hf[(size_t)row * 128 + col];
        out[(size_t)row * 128 + col] = uu * hv + (1.f - uu) * c;
      }
    }
}

extern "C" void kernel_launch(void* const* d_in, const int* in_sizes, int n_in,
                              void* d_out, int out_size, void* d_ws, size_t ws_size,
                              hipStream_t stream) {
  const float* x     = (const float*)d_in[0];
  const void*  ei    = d_in[1];
  const float* h     = (const float*)d_in[3];
  const float* Wl    = (const float*)d_in[4];
  const float* Wr    = (const float*)d_in[5];
  const float* att   = (const float*)d_in[6];
  const float* bconv = (const float*)d_in[7];
  const float* W1    = (const float*)d_in[8];
  const float* b1    = (const float*)d_in[9];
  const float* W2    = (const float*)d_in[10];
  const float* b2    = (const float*)d_in[11];
  float* out = (float*)d_out;

  const int n = in_sizes[0] / 128;   // 50000
  const int E = in_sizes[1] / 2;     // 800000
  const int nbk = (n + 127) >> 7;    // 391

  char* w = (char*)d_ws;
  size_t o = 0;
  auto alloc = [&](size_t bytes) {
    char* p = w + o;
    o += bytes;
    o = (o + 255) & ~(size_t)255;
    return p;
  };
  int* flag         = (int*)alloc(4);
  int* bucketCnt    = (int*)alloc((size_t)nbk * 4);
  int* bucketBase   = (int*)alloc((size_t)(nbk + 1) * 4);
  int* bucketCursor = (int*)alloc((size_t)nbk * 4);
  int* off          = (int*)alloc((size_t)(n + 1) * 4);
  int* csr          = (int*)alloc((size_t)E * 4);
  unsigned long long* pairBuf = (unsigned long long*)alloc((size_t)E * 8);
  unsigned short* xl   = (unsigned short*)alloc((size_t)n * 128 * 2);
  unsigned short* xr   = (unsigned short*)alloc((size_t)n * 128 * 2);
  unsigned short* fbuf = (unsigned short*)alloc((size_t)n * 128 * 2);
  unsigned short* Btfxw = (unsigned short*)alloc(4096 * 8 * 2);
  unsigned short* Btf1  = (unsigned short*)alloc(8192 * 8 * 2);
  unsigned short* Btf2  = (unsigned short*)alloc(4096 * 8 * 2);

  hipMemsetAsync(bucketCnt, 0, (size_t)nbk * 4, stream);
  detect_kernel<<<1, 1024, 0, stream>>>((const unsigned int*)ei, 2LL * E, flag);
  bucket_hist<<<256, 256, 0, stream>>>(ei, E, flag, bucketCnt, nbk);
  bucket_scan<<<1, 64, 0, stream>>>(bucketCnt, bucketBase, bucketCursor, nbk);
  partition_kernel<<<(E + 4095) / 4096, 256, 0, stream>>>(ei, E, flag, bucketCursor,
                                                          pairBuf, nbk);
  csr_build<<<nbk, 256, 0, stream>>>(pairBuf, bucketBase, off, csr, n, E, nbk);
  wprep<<<64, 256, 0, stream>>>(Wl, Wr, W1, W2, Btfxw, Btf1, Btf2);

  int gblocks = (n + 63) / 64;
  gemm_xw<<<gblocks, 256, 0, stream>>>(x, Btfxw, xl, xr, n);
  node_kernel<<<(n + 3) / 4, 256, 0, stream>>>((const unsigned int*)xl, (const unsigned int*)xr,
                                               att, bconv, off, csr,
                                               (unsigned int*)fbuf, n);
  gemm_fused<<<gblocks, 256, 0, stream>>>(fbuf, h, Btf1, Btf2, b1, b2, out, n);
}